// Round 1
// baseline (198.772 us; speedup 1.0000x reference)
//
#include <hip/hip_runtime.h>

// AttentionLayer: out = softmax(Q @ V^T) @ V
// B=4, SQ=SKV=4096, D=64, fp32 in/out.
//
// Strategy: flash-attention with bf16 MFMA (16x16x32).
//  - prep_kernel: V fp32 -> v_hi, v_lo (bf16, row-major [kv][d]) and
//    v_hi^T (bf16, [d][kv]) into workspace. Transposed copy needed because
//    PV contracts over kv (B-operand wants kv-consecutive), QK^T over d.
//  - attn_kernel: 3-pass split-bf16 QK^T (fp32-accurate scores; softmax here
//    is sharply peaked so plain bf16 scores would risk the 0.101 threshold),
//    online softmax in exp2 domain (log2e folded into Q), bf16 P@V.
//  - P layout transform (MFMA C-layout -> A-layout) via per-wave LDS
//    round-trip: packed b64 writes (4 consecutive rows per C-reg group),
//    u16 gather reads. Per-wave buffer -> in-wave lgkmcnt ordering, no barrier.

#define NB   4
#define SQ   4096
#define SKV  4096
#define DH   64
#define L2E  1.44269504088896340736f

typedef __attribute__((ext_vector_type(8))) short short8;
typedef __attribute__((ext_vector_type(4))) float f32x4;

__device__ __forceinline__ unsigned short f2bf(float f) {
  unsigned int u = __builtin_bit_cast(unsigned int, f);
  u += 0x7FFFu + ((u >> 16) & 1u);          // round-to-nearest-even
  return (unsigned short)(u >> 16);
}
__device__ __forceinline__ float bf2f(unsigned short h) {
  unsigned int u = ((unsigned int)h) << 16;
  return __builtin_bit_cast(float, u);
}

// ---------------------------------------------------------------- prep ----
// grid: NB * (SKV/64) blocks, 256 threads. One 64(kv) x 64(d) tile per block.
__global__ __launch_bounds__(256) void prep_kernel(
    const float* __restrict__ V,
    unsigned short* __restrict__ vh,   // [NB][SKV][DH] bf16 hi
    unsigned short* __restrict__ vl,   // [NB][SKV][DH] bf16 lo (residual)
    unsigned short* __restrict__ vt) { // [NB][DH][SKV] bf16 hi, transposed
  __shared__ __align__(16) unsigned short ldsT[64 * 72];  // [d][j], padded
  int blk = blockIdx.x;
  int b   = blk >> 6;
  int j0  = (blk & 63) << 6;
  int t   = threadIdx.x;
  int r   = t >> 2;          // kv row in tile, 0..63
  int dc  = (t & 3) << 4;    // d chunk base: 0,16,32,48

  const float* src = V + ((b * SKV) + j0 + r) * DH + dc;
  __align__(16) unsigned short hi[16];
  __align__(16) unsigned short lo[16];
#pragma unroll
  for (int i = 0; i < 4; ++i) {
    float4 v4 = ((const float4*)src)[i];
    float xs[4] = {v4.x, v4.y, v4.z, v4.w};
#pragma unroll
    for (int k = 0; k < 4; ++k) {
      int idx = i * 4 + k;
      unsigned short h = f2bf(xs[k]);
      hi[idx] = h;
      lo[idx] = f2bf(xs[k] - bf2f(h));
    }
  }
  int go = ((b * SKV) + j0 + r) * DH + dc;
  *(short8*)(vh + go)     = *(const short8*)(hi);
  *(short8*)(vh + go + 8) = *(const short8*)(hi + 8);
  *(short8*)(vl + go)     = *(const short8*)(lo);
  *(short8*)(vl + go + 8) = *(const short8*)(lo + 8);

  // transpose hi through LDS (scattered b16 writes; one-time cost)
#pragma unroll
  for (int i = 0; i < 16; ++i) ldsT[(dc + i) * 72 + r] = hi[i];
  __syncthreads();

  int d  = t >> 2;           // d row, 0..63
  int jc = (t & 3) << 4;     // j chunk: 0,16,32,48
  __align__(16) unsigned short tr[16];
#pragma unroll
  for (int i = 0; i < 16; ++i) tr[i] = ldsT[d * 72 + jc + i];
  int gt = (b * DH + d) * SKV + j0 + jc;
  *(short8*)(vt + gt)     = *(const short8*)(tr);
  *(short8*)(vt + gt + 8) = *(const short8*)(tr + 8);
}

// ---------------------------------------------------------------- attn ----
// grid: NB * (SQ/64) blocks, 256 threads (4 waves, 16 q-rows each).
__global__ __launch_bounds__(256) void attn_kernel(
    const float* __restrict__ Q,
    const unsigned short* __restrict__ vh,
    const unsigned short* __restrict__ vl,
    const unsigned short* __restrict__ vt,
    float* __restrict__ out) {
  // 72-elem row stride: 144 B = 36 banks -> (row+quad) mod 8 uniform, no
  // b128 bank skew. Do NOT use global_load_lds here: padding breaks its
  // wave-uniform-base+lane*16 layout rule.
  __shared__ __align__(16) unsigned short s_vh[64 * 72];
  __shared__ __align__(16) unsigned short s_vl[64 * 72];
  __shared__ __align__(16) unsigned short s_vt[64 * 72];
  __shared__ __align__(16) unsigned short s_pt[4][64 * 20];  // per-wave P^T [j][m]

  int blk  = blockIdx.x;
  int b    = blk >> 6;
  int q0   = (blk & 63) << 6;
  int t    = threadIdx.x;
  int wave = t >> 6;
  int lane = t & 63;
  int col  = lane & 15;      // C-frag col / A-frag m
  int quad = lane >> 4;
  int qw   = q0 + (wave << 4);

  // ---- Q fragments (A-operand: m=lane&15, k=quad*8+j), *log2e, hi/lo split
  short8 qhf[2], qlf[2];
  {
    const float* qp = Q + (b * SQ + qw + col) * DH + (quad << 3);
#pragma unroll
    for (int kc = 0; kc < 2; ++kc) {
      float4 a0 = *(const float4*)(qp + kc * 32);
      float4 a1 = *(const float4*)(qp + kc * 32 + 4);
      float xs[8] = {a0.x, a0.y, a0.z, a0.w, a1.x, a1.y, a1.z, a1.w};
      short8 h, l;
#pragma unroll
      for (int j = 0; j < 8; ++j) {
        float x = xs[j] * L2E;
        unsigned short hh = f2bf(x);
        h[j] = (short)hh;
        l[j] = (short)f2bf(x - bf2f(hh));
      }
      qhf[kc] = h;
      qlf[kc] = l;
    }
  }

  f32x4 o[4];
#pragma unroll
  for (int nf = 0; nf < 4; ++nf) o[nf] = (f32x4){0.f, 0.f, 0.f, 0.f};
  float m_r[4] = {-1e30f, -1e30f, -1e30f, -1e30f};  // log2-domain running max
  float l_r[4] = {0.f, 0.f, 0.f, 0.f};              // per-lane partial row sum

  int sr = t >> 2;           // staging row 0..63
  int sc = (t & 3) << 4;     // staging col chunk
  const unsigned short* gvh = vh + (b * SKV) * DH;
  const unsigned short* gvl = vl + (b * SKV) * DH;
  const unsigned short* gvt = vt + (b * DH) * SKV;

  for (int j0 = 0; j0 < SKV; j0 += 64) {
    __syncthreads();  // previous tile's LDS reads done
    {
      int g = (j0 + sr) * DH + sc;
      short8 a0 = *(const short8*)(gvh + g);
      short8 a1 = *(const short8*)(gvh + g + 8);
      short8 b0 = *(const short8*)(gvl + g);
      short8 b1 = *(const short8*)(gvl + g + 8);
      int gt = sr * SKV + j0 + sc;
      short8 c0 = *(const short8*)(gvt + gt);
      short8 c1 = *(const short8*)(gvt + gt + 8);
      int l0 = sr * 72 + sc;
      *(short8*)(s_vh + l0)     = a0;
      *(short8*)(s_vh + l0 + 8) = a1;
      *(short8*)(s_vl + l0)     = b0;
      *(short8*)(s_vl + l0 + 8) = b1;
      *(short8*)(s_vt + l0)     = c0;
      *(short8*)(s_vt + l0 + 8) = c1;
    }
    __syncthreads();

    // ---- S = (Q*log2e) @ V^T, 3-pass split bf16, fp32 accum
    f32x4 s[4];
#pragma unroll
    for (int nf = 0; nf < 4; ++nf) s[nf] = (f32x4){0.f, 0.f, 0.f, 0.f};
#pragma unroll
    for (int nf = 0; nf < 4; ++nf) {
#pragma unroll
      for (int kc = 0; kc < 2; ++kc) {
        int off = (nf * 16 + col) * 72 + kc * 32 + (quad << 3);
        short8 bh = *(const short8*)(s_vh + off);
        short8 bl = *(const short8*)(s_vl + off);
        s[nf] = __builtin_amdgcn_mfma_f32_16x16x32_bf16(qhf[kc], bh, s[nf], 0, 0, 0);
        s[nf] = __builtin_amdgcn_mfma_f32_16x16x32_bf16(qlf[kc], bh, s[nf], 0, 0, 0);
        s[nf] = __builtin_amdgcn_mfma_f32_16x16x32_bf16(qhf[kc], bl, s[nf], 0, 0, 0);
      }
    }

    // ---- online softmax (exp2 domain); C-frag row = quad*4 + r
    float tm[4];
#pragma unroll
    for (int r = 0; r < 4; ++r)
      tm[r] = fmaxf(fmaxf(s[0][r], s[1][r]), fmaxf(s[2][r], s[3][r]));
#pragma unroll
    for (int mask = 1; mask <= 8; mask <<= 1) {
#pragma unroll
      for (int r = 0; r < 4; ++r)
        tm[r] = fmaxf(tm[r], __shfl_xor(tm[r], mask, 64));
    }
    float al[4];
#pragma unroll
    for (int r = 0; r < 4; ++r) {
      float mn = fmaxf(m_r[r], tm[r]);
      al[r] = exp2f(m_r[r] - mn);
      m_r[r] = mn;
    }
    float rs[4] = {0.f, 0.f, 0.f, 0.f};
#pragma unroll
    for (int nf = 0; nf < 4; ++nf) {
#pragma unroll
      for (int r = 0; r < 4; ++r) {
        float p = exp2f(s[nf][r] - m_r[r]);
        s[nf][r] = p;
        rs[r] += p;
      }
    }
#pragma unroll
    for (int r = 0; r < 4; ++r) l_r[r] = l_r[r] * al[r] + rs[r];
#pragma unroll
    for (int nf = 0; nf < 4; ++nf) {
#pragma unroll
      for (int r = 0; r < 4; ++r) o[nf][r] *= al[r];
    }

    // ---- P^T -> per-wave LDS (b64 packed: regs 0..3 are consecutive rows)
    unsigned short* pt = &s_pt[wave][0];
#pragma unroll
    for (int nf = 0; nf < 4; ++nf) {
      int j = nf * 16 + col;
      unsigned long long pk =
          (unsigned long long)f2bf(s[nf][0]) |
          ((unsigned long long)f2bf(s[nf][1]) << 16) |
          ((unsigned long long)f2bf(s[nf][2]) << 32) |
          ((unsigned long long)f2bf(s[nf][3]) << 48);
      *(unsigned long long*)(pt + j * 20 + (quad << 2)) = pk;
    }

    // ---- O += P @ V  (A-frag: P[m=col][k=quad*8+j], B-frag from v^T)
#pragma unroll
    for (int kc = 0; kc < 2; ++kc) {
      short8 pa;
#pragma unroll
      for (int jj = 0; jj < 8; ++jj)
        pa[jj] = (short)pt[(kc * 32 + (quad << 3) + jj) * 20 + col];
#pragma unroll
      for (int nf = 0; nf < 4; ++nf) {
        short8 bv = *(const short8*)(s_vt + (nf * 16 + col) * 72 + kc * 32 + (quad << 3));
        o[nf] = __builtin_amdgcn_mfma_f32_16x16x32_bf16(pa, bv, o[nf], 0, 0, 0);
      }
    }
  }

  // ---- epilogue: finish row-sum reduction across the 16 cols, normalize
#pragma unroll
  for (int mask = 1; mask <= 8; mask <<= 1) {
#pragma unroll
    for (int r = 0; r < 4; ++r) l_r[r] += __shfl_xor(l_r[r], mask, 64);
  }
  float* op = out + (b * SQ + qw) * DH;
#pragma unroll
  for (int r = 0; r < 4; ++r) {
    float inv = 1.0f / l_r[r];
#pragma unroll
    for (int nf = 0; nf < 4; ++nf)
      op[((quad << 2) + r) * DH + nf * 16 + col] = o[nf][r] * inv;
  }
}

// -------------------------------------------------------------- launch ----
extern "C" void kernel_launch(void* const* d_in, const int* in_sizes, int n_in,
                              void* d_out, int out_size, void* d_ws, size_t ws_size,
                              hipStream_t stream) {
  const float* Q = (const float*)d_in[0];
  const float* V = (const float*)d_in[1];
  float* out = (float*)d_out;
  unsigned short* w  = (unsigned short*)d_ws;  // need 6 MB: 3 bf16 copies of V
  unsigned short* vh = w;
  unsigned short* vl = w + (size_t)NB * SKV * DH;
  unsigned short* vt = w + (size_t)2 * NB * SKV * DH;
  prep_kernel<<<NB * (SKV / 64), 256, 0, stream>>>(V, vh, vl, vt);
  attn_kernel<<<NB * (SQ / 64), 256, 0, stream>>>(Q, vh, vl, vt, out);
}

// Round 2
// 137.259 us; speedup vs baseline: 1.4482x; 1.4482x over previous
//
#include <hip/hip_runtime.h>

// AttentionLayer: out = softmax(Q @ V^T) @ V ; B=4, SQ=SKV=4096, D=64, fp32.
//
// R1 change: KV-split flash attention. R0 counters showed Occupancy=11.4%
// (grid 256 = 1 block/CU, latency-bound; MfmaUtil 9.2, VALUBusy 26.6, HBM 2.7%).
// Split KV into S=4 ranges -> grid 1024 -> 4 blocks/CU (LDS 37888*4 = 148 KB
// fits 160 KB), partials (unnormalized O, m, l) in workspace, combine kernel
// rescales. prep regridded to 1024 blocks (was 256, also 1 block/CU).

#define NB   4
#define SQ   4096
#define SKV  4096
#define DH   64
#define L2E  1.44269504088896340736f

typedef __attribute__((ext_vector_type(8))) short short8;
typedef __attribute__((ext_vector_type(4))) short short4v;
typedef __attribute__((ext_vector_type(4))) float f32x4;

__device__ __forceinline__ unsigned short f2bf(float f) {
  unsigned int u = __builtin_bit_cast(unsigned int, f);
  u += 0x7FFFu + ((u >> 16) & 1u);          // round-to-nearest-even
  return (unsigned short)(u >> 16);
}
__device__ __forceinline__ float bf2f(unsigned short h) {
  unsigned int u = ((unsigned int)h) << 16;
  return __builtin_bit_cast(float, u);
}

// ---------------------------------------------------------------- prep ----
// grid: NB*256 blocks (tile = 64 kv-rows x 16 d-cols), 256 threads.
__global__ __launch_bounds__(256) void prep_kernel(
    const float* __restrict__ V,
    unsigned short* __restrict__ vh,   // [NB][SKV][DH] bf16 hi
    unsigned short* __restrict__ vl,   // [NB][SKV][DH] bf16 lo (residual)
    unsigned short* __restrict__ vt) { // [NB][DH][SKV] bf16 hi, transposed
  __shared__ __align__(16) unsigned short ldsT[16 * 72];
  int blk = blockIdx.x;
  int b   = blk >> 8;
  int rem = blk & 255;
  int j0  = (rem >> 2) << 6;   // kv tile base
  int d0  = (rem & 3) << 4;    // d tile base
  int t   = threadIdx.x;
  int j   = t >> 2;            // 0..63
  int dc  = (t & 3) << 2;      // 0,4,8,12

  const float* src = V + ((size_t)(b * SKV) + j0 + j) * DH + d0 + dc;
  float4 v4 = *(const float4*)src;
  float xs[4] = {v4.x, v4.y, v4.z, v4.w};
  short4v hi, lo;
#pragma unroll
  for (int k = 0; k < 4; ++k) {
    unsigned short h = f2bf(xs[k]);
    hi[k] = (short)h;
    lo[k] = (short)f2bf(xs[k] - bf2f(h));
  }
  size_t go = ((size_t)(b * SKV) + j0 + j) * DH + d0 + dc;
  *(short4v*)(vh + go) = hi;
  *(short4v*)(vl + go) = lo;

  // transpose hi tile (16 d x 64 j) through LDS
#pragma unroll
  for (int k = 0; k < 4; ++k) ldsT[(dc + k) * 72 + j] = (unsigned short)hi[k];
  __syncthreads();

  int dl = t >> 4;             // 0..15
  int jc = (t & 15) << 2;      // 0..60
  short4v tr;
#pragma unroll
  for (int k = 0; k < 4; ++k) tr[k] = (short)ldsT[dl * 72 + jc + k];
  *(short4v*)(vt + ((size_t)(b * DH) + d0 + dl) * SKV + j0 + jc) = tr;
}

// ---------------------------------------------------------------- attn ----
// grid: NB*(SQ/64)*S blocks, 256 threads (4 waves, 16 q-rows each).
// Each block handles KV range [s*kvLen, (s+1)*kvLen), writes unnormalized
// partial O + per-row (m, l) to workspace.
__global__ __launch_bounds__(256, 4) void attn_kernel(
    const float* __restrict__ Q,
    const unsigned short* __restrict__ vh,
    const unsigned short* __restrict__ vl,
    const unsigned short* __restrict__ vt,
    float* __restrict__ po,  // [NB*64*S][64][64] unnormalized O
    float* __restrict__ pm,  // [NB*64*S][64] running max (log2 domain)
    float* __restrict__ pl,  // [NB*64*S][64] running sum
    int S, int kvLen) {
  __shared__ __align__(16) unsigned short s_vh[64 * 72];
  __shared__ __align__(16) unsigned short s_vl[64 * 72];
  __shared__ __align__(16) unsigned short s_vt[64 * 72];
  __shared__ __align__(16) unsigned short s_pt[4][64 * 20];  // per-wave P^T [j][m]

  int blk  = blockIdx.x;
  int tile = blk / S;          // b*64 + qtile
  int s    = blk - tile * S;
  int b    = tile >> 6;
  int q0   = (tile & 63) << 6;
  int kv0  = s * kvLen;
  int kv1  = kv0 + kvLen;
  int t    = threadIdx.x;
  int wave = t >> 6;
  int lane = t & 63;
  int col  = lane & 15;
  int quad = lane >> 4;
  int qw   = q0 + (wave << 4);

  // ---- Q fragments (A-operand: m=lane&15, k=quad*8+j), *log2e, hi/lo split
  short8 qhf[2], qlf[2];
  {
    const float* qp = Q + ((size_t)(b * SQ) + qw + col) * DH + (quad << 3);
#pragma unroll
    for (int kc = 0; kc < 2; ++kc) {
      float4 a0 = *(const float4*)(qp + kc * 32);
      float4 a1 = *(const float4*)(qp + kc * 32 + 4);
      float xs[8] = {a0.x, a0.y, a0.z, a0.w, a1.x, a1.y, a1.z, a1.w};
      short8 h, l;
#pragma unroll
      for (int j = 0; j < 8; ++j) {
        float x = xs[j] * L2E;
        unsigned short hh = f2bf(x);
        h[j] = (short)hh;
        l[j] = (short)f2bf(x - bf2f(hh));
      }
      qhf[kc] = h;
      qlf[kc] = l;
    }
  }

  f32x4 o[4];
#pragma unroll
  for (int nf = 0; nf < 4; ++nf) o[nf] = (f32x4){0.f, 0.f, 0.f, 0.f};
  float m_r[4] = {-1e30f, -1e30f, -1e30f, -1e30f};
  float l_r[4] = {0.f, 0.f, 0.f, 0.f};

  int sr = t >> 2;
  int sc = (t & 3) << 4;
  const unsigned short* gvh = vh + (size_t)(b * SKV) * DH;
  const unsigned short* gvl = vl + (size_t)(b * SKV) * DH;
  const unsigned short* gvt = vt + (size_t)(b * DH) * SKV;

  for (int j0 = kv0; j0 < kv1; j0 += 64) {
    __syncthreads();
    {
      size_t g = (size_t)(j0 + sr) * DH + sc;
      short8 a0 = *(const short8*)(gvh + g);
      short8 a1 = *(const short8*)(gvh + g + 8);
      short8 b0 = *(const short8*)(gvl + g);
      short8 b1 = *(const short8*)(gvl + g + 8);
      size_t gt = (size_t)sr * SKV + j0 + sc;
      short8 c0 = *(const short8*)(gvt + gt);
      short8 c1 = *(const short8*)(gvt + gt + 8);
      int l0 = sr * 72 + sc;
      *(short8*)(s_vh + l0)     = a0;
      *(short8*)(s_vh + l0 + 8) = a1;
      *(short8*)(s_vl + l0)     = b0;
      *(short8*)(s_vl + l0 + 8) = b1;
      *(short8*)(s_vt + l0)     = c0;
      *(short8*)(s_vt + l0 + 8) = c1;
    }
    __syncthreads();

    // ---- S = (Q*log2e) @ V^T, 3-pass split bf16
    f32x4 sf[4];
#pragma unroll
    for (int nf = 0; nf < 4; ++nf) sf[nf] = (f32x4){0.f, 0.f, 0.f, 0.f};
#pragma unroll
    for (int nf = 0; nf < 4; ++nf) {
#pragma unroll
      for (int kc = 0; kc < 2; ++kc) {
        int off = (nf * 16 + col) * 72 + kc * 32 + (quad << 3);
        short8 bh = *(const short8*)(s_vh + off);
        short8 bl = *(const short8*)(s_vl + off);
        sf[nf] = __builtin_amdgcn_mfma_f32_16x16x32_bf16(qhf[kc], bh, sf[nf], 0, 0, 0);
        sf[nf] = __builtin_amdgcn_mfma_f32_16x16x32_bf16(qlf[kc], bh, sf[nf], 0, 0, 0);
        sf[nf] = __builtin_amdgcn_mfma_f32_16x16x32_bf16(qhf[kc], bl, sf[nf], 0, 0, 0);
      }
    }

    // ---- online softmax (exp2 domain)
    float tm[4];
#pragma unroll
    for (int r = 0; r < 4; ++r)
      tm[r] = fmaxf(fmaxf(sf[0][r], sf[1][r]), fmaxf(sf[2][r], sf[3][r]));
#pragma unroll
    for (int mask = 1; mask <= 8; mask <<= 1) {
#pragma unroll
      for (int r = 0; r < 4; ++r)
        tm[r] = fmaxf(tm[r], __shfl_xor(tm[r], mask, 64));
    }
    float al[4];
#pragma unroll
    for (int r = 0; r < 4; ++r) {
      float mn = fmaxf(m_r[r], tm[r]);
      al[r] = exp2f(m_r[r] - mn);
      m_r[r] = mn;
    }
    float rs[4] = {0.f, 0.f, 0.f, 0.f};
#pragma unroll
    for (int nf = 0; nf < 4; ++nf) {
#pragma unroll
      for (int r = 0; r < 4; ++r) {
        float p = exp2f(sf[nf][r] - m_r[r]);
        sf[nf][r] = p;
        rs[r] += p;
      }
    }
#pragma unroll
    for (int r = 0; r < 4; ++r) l_r[r] = l_r[r] * al[r] + rs[r];
#pragma unroll
    for (int nf = 0; nf < 4; ++nf) {
#pragma unroll
      for (int r = 0; r < 4; ++r) o[nf][r] *= al[r];
    }

    // ---- P^T -> per-wave LDS (C-layout -> A-layout round trip)
    unsigned short* pt = &s_pt[wave][0];
#pragma unroll
    for (int nf = 0; nf < 4; ++nf) {
      int j = nf * 16 + col;
      unsigned long long pk =
          (unsigned long long)f2bf(sf[nf][0]) |
          ((unsigned long long)f2bf(sf[nf][1]) << 16) |
          ((unsigned long long)f2bf(sf[nf][2]) << 32) |
          ((unsigned long long)f2bf(sf[nf][3]) << 48);
      *(unsigned long long*)(pt + j * 20 + (quad << 2)) = pk;
    }

    // ---- O += P @ V
#pragma unroll
    for (int kc = 0; kc < 2; ++kc) {
      short8 pa;
#pragma unroll
      for (int jj = 0; jj < 8; ++jj)
        pa[jj] = (short)pt[(kc * 32 + (quad << 3) + jj) * 20 + col];
#pragma unroll
      for (int nf = 0; nf < 4; ++nf) {
        short8 bv = *(const short8*)(s_vt + (nf * 16 + col) * 72 + kc * 32 + (quad << 3));
        o[nf] = __builtin_amdgcn_mfma_f32_16x16x32_bf16(pa, bv, o[nf], 0, 0, 0);
      }
    }
  }

  // ---- epilogue: reduce l across 16 cols, write unnormalized partials
#pragma unroll
  for (int mask = 1; mask <= 8; mask <<= 1) {
#pragma unroll
    for (int r = 0; r < 4; ++r) l_r[r] += __shfl_xor(l_r[r], mask, 64);
  }
  int pidx = tile * S + s;
  float* pob = po + (size_t)pidx * 4096 + (size_t)(wave << 4) * 64;
#pragma unroll
  for (int r = 0; r < 4; ++r) {
#pragma unroll
    for (int nf = 0; nf < 4; ++nf)
      pob[((quad << 2) + r) * 64 + nf * 16 + col] = o[nf][r];
  }
  if (col == 0) {
    int row = (wave << 4) + (quad << 2);
#pragma unroll
    for (int r = 0; r < 4; ++r) {
      pm[(size_t)pidx * 64 + row + r] = m_r[r];
      pl[(size_t)pidx * 64 + row + r] = l_r[r];
    }
  }
}

// ------------------------------------------------------------- combine ----
// grid: NB*64*2 blocks, 256 threads; each block = half a q-tile (32 rows).
__global__ __launch_bounds__(256) void combine_kernel(
    const float* __restrict__ po,
    const float* __restrict__ pm,
    const float* __restrict__ pl,
    float* __restrict__ out, int S) {
  int blk  = blockIdx.x;
  int tile = blk >> 1;
  int half = blk & 1;
  int t    = threadIdx.x;
  int q    = (half << 5) + (t >> 3);   // 0..63
  int dc   = (t & 7) << 3;             // 0..56

  float mv[4], lv[4];
  float M = -1e30f;
  for (int s = 0; s < S; ++s) {
    mv[s] = pm[(size_t)(tile * S + s) * 64 + q];
    lv[s] = pl[(size_t)(tile * S + s) * 64 + q];
    M = fmaxf(M, mv[s]);
  }
  float L = 0.f;
  float w[4];
  for (int s = 0; s < S; ++s) {
    w[s] = exp2f(mv[s] - M);
    L += lv[s] * w[s];
  }
  float invL = 1.0f / L;
  f32x4 a0 = (f32x4){0.f, 0.f, 0.f, 0.f}, a1 = a0;
  for (int s = 0; s < S; ++s) {
    const float* p = po + (size_t)(tile * S + s) * 4096 + q * 64 + dc;
    f32x4 x0 = *(const f32x4*)p;
    f32x4 x1 = *(const f32x4*)(p + 4);
    a0 += x0 * w[s];
    a1 += x1 * w[s];
  }
  float* op = out + (size_t)tile * 4096 + q * 64 + dc;
  *(f32x4*)op       = a0 * invL;
  *(f32x4*)(op + 4) = a1 * invL;
}

// -------------------------------------------------------------- launch ----
extern "C" void kernel_launch(void* const* d_in, const int* in_sizes, int n_in,
                              void* d_out, int out_size, void* d_ws, size_t ws_size,
                              hipStream_t stream) {
  const float* Q = (const float*)d_in[0];
  const float* V = (const float*)d_in[1];
  float* out = (float*)d_out;

  const size_t convBytes = (size_t)3 * NB * SKV * DH * 2;  // 6 MB
  auto partBytes = [](int S) {
    return (size_t)NB * 64 * S * (4096 + 128) * 4;
  };
  int S = 4;
  if (ws_size < convBytes + partBytes(4)) S = 2;
  if (ws_size < convBytes + partBytes(2)) S = 1;
  int kvLen = SKV / S;

  unsigned short* w  = (unsigned short*)d_ws;
  unsigned short* vh = w;
  unsigned short* vl = w + (size_t)NB * SKV * DH;
  unsigned short* vt = w + (size_t)2 * NB * SKV * DH;
  float* po = (float*)((char*)d_ws + convBytes);
  float* pm = po + (size_t)NB * 64 * S * 4096;
  float* pl = pm + (size_t)NB * 64 * S * 64;

  prep_kernel<<<NB * 256, 256, 0, stream>>>(V, vh, vl, vt);
  attn_kernel<<<NB * 64 * S, 256, 0, stream>>>(Q, vh, vl, vt, po, pm, pl, S, kvLen);
  combine_kernel<<<NB * 64 * 2, 256, 0, stream>>>(po, pm, pl, out, S);
}

// Round 4
// 119.001 us; speedup vs baseline: 1.6703x; 1.1534x over previous
//
#include <hip/hip_runtime.h>

// AttentionLayer: out = softmax(Q @ V^T) @ V ; B=4, SQ=SKV=4096, D=64, fp32.
//
// R2/R3: fp16 single-pass MFMA (fp16 11-bit mantissa: S err ~0.004, output
// err ~0.015 vs threshold 0.101), M=32 q-rows/wave (block = 128 rows) to
// amortize B-fragment LDS reads, stride-20 P^T buffer (2-way banks = free),
// fp16 partial-O, S=8 KV split (grid 1024 = 4 blocks/CU; LDS 38.9 KB).
// R3 fix: __hmax2 -> __builtin_elementwise_max on _Float16x2 (ROCm 7.2's
// __hmax2 overload set rejects __half2 from bit_cast; the builtin emits
// v_pk_max_f16 directly).

#define NB   4
#define SQ   4096
#define SKV  4096
#define DH   64
#define L2E  1.44269504088896340736f

typedef _Float16 half8 __attribute__((ext_vector_type(8)));
typedef _Float16 half2v __attribute__((ext_vector_type(2)));
typedef __attribute__((ext_vector_type(4))) float f32x4;
typedef unsigned short u16;

__device__ __forceinline__ u16 f2h(float f) {
  _Float16 h = (_Float16)f;
  return __builtin_bit_cast(u16, h);
}

// ---------------------------------------------------------------- prep ----
// V fp32 -> vh fp16 [b][j][d] and vt fp16 [b][d][j]. grid NB*256, 256 thr.
__global__ __launch_bounds__(256) void prep_kernel(
    const float* __restrict__ V, u16* __restrict__ vh, u16* __restrict__ vt) {
  __shared__ u16 ldsT[16 * 72];
  int blk = blockIdx.x;
  int b   = blk >> 8;
  int rem = blk & 255;
  int j0  = (rem >> 2) << 6;   // kv tile base
  int d0  = (rem & 3) << 4;    // d tile base
  int t   = threadIdx.x;
  int j   = t >> 2;            // 0..63
  int dc  = (t & 3) << 2;      // 0,4,8,12

  const float* src = V + ((size_t)(b * SKV) + j0 + j) * DH + d0 + dc;
  float4 v4 = *(const float4*)src;
  u16 h[4] = {f2h(v4.x), f2h(v4.y), f2h(v4.z), f2h(v4.w)};
  unsigned p0 = (unsigned)h[0] | ((unsigned)h[1] << 16);
  unsigned p1 = (unsigned)h[2] | ((unsigned)h[3] << 16);
  size_t go = ((size_t)(b * SKV) + j0 + j) * DH + d0 + dc;
  *(uint2*)(vh + go) = make_uint2(p0, p1);

#pragma unroll
  for (int k = 0; k < 4; ++k) ldsT[(dc + k) * 72 + j] = h[k];
  __syncthreads();

  int dl = t >> 4;             // 0..15
  int jc = (t & 15) << 2;      // 0..60
  u16 tr[4];
#pragma unroll
  for (int k = 0; k < 4; ++k) tr[k] = ldsT[dl * 72 + jc + k];
  unsigned q0 = (unsigned)tr[0] | ((unsigned)tr[1] << 16);
  unsigned q1 = (unsigned)tr[2] | ((unsigned)tr[3] << 16);
  *(uint2*)(vt + ((size_t)(b * DH) + d0 + dl) * SKV + j0 + jc) = make_uint2(q0, q1);
}

// ---------------------------------------------------------------- attn ----
// grid NB*32*S blocks, 256 threads = 4 waves * 32 q-rows (2 sets of 16).
__global__ __launch_bounds__(256, 4) void attn_kernel(
    const float* __restrict__ Q,
    const u16* __restrict__ vh,
    const u16* __restrict__ vt,
    u16* __restrict__ po,    // [NB*32*S][128][64] fp16 unnormalized O
    float* __restrict__ pm,  // [NB*32*S][128] running max (log2 domain)
    float* __restrict__ pl,  // [NB*32*S][128] running sum
    int S, int kvLen) {
  __shared__ __align__(16) u16 s_v[64 * 72];    // V tile [j][d]
  __shared__ __align__(16) u16 s_vt[64 * 72];   // V^T tile [d][j]
  __shared__ __align__(16) u16 s_pt[8][64 * 20]; // per wave*set P^T [j][m]

  int blk  = blockIdx.x;
  int tile = blk / S;          // b*32 + qtile
  int s    = blk - tile * S;
  int b    = tile >> 5;
  int q0   = (tile & 31) << 7;
  int kv0  = s * kvLen;
  int t    = threadIdx.x;
  int wave = t >> 6;
  int lane = t & 63;
  int col  = lane & 15;
  int quad = lane >> 4;
  int qw   = q0 + (wave << 5);

  // ---- Q fragments (A: m=lane&15, k=quad*8+j), fp16, log2e folded in
  half8 qf[2][2];
#pragma unroll
  for (int set = 0; set < 2; ++set) {
#pragma unroll
    for (int kc = 0; kc < 2; ++kc) {
      const float* qp = Q + ((size_t)(b * SQ) + qw + set * 16 + col) * DH +
                        kc * 32 + (quad << 3);
      float4 a0 = *(const float4*)qp;
      float4 a1 = *(const float4*)(qp + 4);
      half8 h;
      h[0] = (_Float16)(a0.x * L2E); h[1] = (_Float16)(a0.y * L2E);
      h[2] = (_Float16)(a0.z * L2E); h[3] = (_Float16)(a0.w * L2E);
      h[4] = (_Float16)(a1.x * L2E); h[5] = (_Float16)(a1.y * L2E);
      h[6] = (_Float16)(a1.z * L2E); h[7] = (_Float16)(a1.w * L2E);
      qf[set][kc] = h;
    }
  }

  f32x4 o[2][4];
  float m_r[2][4], l_r[2][4];
#pragma unroll
  for (int set = 0; set < 2; ++set)
#pragma unroll
    for (int nf = 0; nf < 4; ++nf) {
      o[set][nf] = (f32x4){0.f, 0.f, 0.f, 0.f};
      m_r[set][nf] = -1e30f;
      l_r[set][nf] = 0.f;
    }

  int sr = t >> 2;
  int sc = (t & 3) << 4;
  const u16* gv  = vh + (size_t)(b * SKV) * DH;
  const u16* gvt = vt + (size_t)(b * DH) * SKV;

  for (int j0 = kv0; j0 < kv0 + kvLen; j0 += 64) {
    __syncthreads();
    {
      size_t g = (size_t)(j0 + sr) * DH + sc;
      uint4 a0 = *(const uint4*)(gv + g);
      uint4 a1 = *(const uint4*)(gv + g + 8);
      size_t gt = (size_t)sr * SKV + j0 + sc;
      uint4 c0 = *(const uint4*)(gvt + gt);
      uint4 c1 = *(const uint4*)(gvt + gt + 8);
      int l0 = sr * 72 + sc;
      *(uint4*)(s_v + l0)      = a0;
      *(uint4*)(s_v + l0 + 8)  = a1;
      *(uint4*)(s_vt + l0)     = c0;
      *(uint4*)(s_vt + l0 + 8) = c1;
    }
    __syncthreads();

    // ---- S = Qlog2e @ V^T for both 16-row sets (shared B-frag reads)
    f32x4 sf[2][4];
#pragma unroll
    for (int set = 0; set < 2; ++set)
#pragma unroll
      for (int nf = 0; nf < 4; ++nf) sf[set][nf] = (f32x4){0.f, 0.f, 0.f, 0.f};
#pragma unroll
    for (int nf = 0; nf < 4; ++nf) {
#pragma unroll
      for (int kc = 0; kc < 2; ++kc) {
        half8 bv = *(const half8*)(s_v + (nf * 16 + col) * 72 + kc * 32 + (quad << 3));
        sf[0][nf] = __builtin_amdgcn_mfma_f32_16x16x32_f16(qf[0][kc], bv, sf[0][nf], 0, 0, 0);
        sf[1][nf] = __builtin_amdgcn_mfma_f32_16x16x32_f16(qf[1][kc], bv, sf[1][nf], 0, 0, 0);
      }
    }

    // ---- online softmax per set; P^T -> per-(wave,set) LDS
#pragma unroll
    for (int set = 0; set < 2; ++set) {
      float tm[4];
#pragma unroll
      for (int r = 0; r < 4; ++r)
        tm[r] = fmaxf(fmaxf(sf[set][0][r], sf[set][1][r]),
                      fmaxf(sf[set][2][r], sf[set][3][r]));
      // packed-fp16 butterfly max over the 16 cols (m needs only ~0.1 acc;
      // any m error cancels exactly in normalization)
      half2v h01 = {(_Float16)tm[0], (_Float16)tm[1]};
      half2v h23 = {(_Float16)tm[2], (_Float16)tm[3]};
#pragma unroll
      for (int mask = 1; mask <= 8; mask <<= 1) {
        int i01 = __shfl_xor(__builtin_bit_cast(int, h01), mask, 64);
        int i23 = __shfl_xor(__builtin_bit_cast(int, h23), mask, 64);
        h01 = __builtin_elementwise_max(h01, __builtin_bit_cast(half2v, i01));
        h23 = __builtin_elementwise_max(h23, __builtin_bit_cast(half2v, i23));
      }
      tm[0] = (float)h01[0]; tm[1] = (float)h01[1];
      tm[2] = (float)h23[0]; tm[3] = (float)h23[1];

      float al[4];
#pragma unroll
      for (int r = 0; r < 4; ++r) {
        float mn = fmaxf(m_r[set][r], tm[r]);
        al[r] = exp2f(m_r[set][r] - mn);
        m_r[set][r] = mn;
      }
      float rs[4] = {0.f, 0.f, 0.f, 0.f};
#pragma unroll
      for (int nf = 0; nf < 4; ++nf) {
#pragma unroll
        for (int r = 0; r < 4; ++r) {
          float p = exp2f(sf[set][nf][r] - m_r[set][r]);
          sf[set][nf][r] = p;
          rs[r] += p;
        }
      }
#pragma unroll
      for (int r = 0; r < 4; ++r) l_r[set][r] = l_r[set][r] * al[r] + rs[r];
#pragma unroll
      for (int nf = 0; nf < 4; ++nf)
#pragma unroll
        for (int r = 0; r < 4; ++r) o[set][nf][r] *= al[r];

      u16* pt = &s_pt[wave * 2 + set][0];
#pragma unroll
      for (int nf = 0; nf < 4; ++nf) {
        int j = nf * 16 + col;
        unsigned long long pk =
            (unsigned long long)f2h(sf[set][nf][0]) |
            ((unsigned long long)f2h(sf[set][nf][1]) << 16) |
            ((unsigned long long)f2h(sf[set][nf][2]) << 32) |
            ((unsigned long long)f2h(sf[set][nf][3]) << 48);
        *(unsigned long long*)(pt + j * 20 + (quad << 2)) = pk;
      }
    }

    // ---- O += P @ V (shared V^T B-frags across the two sets)
#pragma unroll
    for (int kc = 0; kc < 2; ++kc) {
      half8 pa0, pa1;
      const u16* pt0 = &s_pt[wave * 2 + 0][0];
      const u16* pt1 = &s_pt[wave * 2 + 1][0];
#pragma unroll
      for (int jj = 0; jj < 8; ++jj) {
        int k = kc * 32 + (quad << 3) + jj;
        pa0[jj] = __builtin_bit_cast(_Float16, pt0[k * 20 + col]);
        pa1[jj] = __builtin_bit_cast(_Float16, pt1[k * 20 + col]);
      }
#pragma unroll
      for (int nf = 0; nf < 4; ++nf) {
        half8 bw = *(const half8*)(s_vt + (nf * 16 + col) * 72 + kc * 32 + (quad << 3));
        o[0][nf] = __builtin_amdgcn_mfma_f32_16x16x32_f16(pa0, bw, o[0][nf], 0, 0, 0);
        o[1][nf] = __builtin_amdgcn_mfma_f32_16x16x32_f16(pa1, bw, o[1][nf], 0, 0, 0);
      }
    }
  }

  // ---- epilogue: exact per-row l reduction, write fp16 partials + (m,l)
#pragma unroll
  for (int set = 0; set < 2; ++set)
#pragma unroll
    for (int mask = 1; mask <= 8; mask <<= 1)
#pragma unroll
      for (int r = 0; r < 4; ++r)
        l_r[set][r] += __shfl_xor(l_r[set][r], mask, 64);

  int pidx = tile * S + s;
  u16* pob = po + (size_t)pidx * 128 * 64;
#pragma unroll
  for (int set = 0; set < 2; ++set) {
#pragma unroll
    for (int nf = 0; nf < 4; ++nf)
#pragma unroll
      for (int r = 0; r < 4; ++r) {
        int row = (wave << 5) + set * 16 + (quad << 2) + r;
        pob[row * 64 + nf * 16 + col] = f2h(o[set][nf][r]);
      }
  }
  if (col == 0) {
#pragma unroll
    for (int set = 0; set < 2; ++set)
#pragma unroll
      for (int r = 0; r < 4; ++r) {
        int row = (wave << 5) + set * 16 + (quad << 2) + r;
        pm[(size_t)pidx * 128 + row] = m_r[set][r];
        pl[(size_t)pidx * 128 + row] = l_r[set][r];
      }
  }
}

// ------------------------------------------------------------- combine ----
// grid NB*SQ/32 blocks, 256 threads; thread = (row, 8-d chunk).
__global__ __launch_bounds__(256) void combine_kernel(
    const u16* __restrict__ po,
    const float* __restrict__ pm,
    const float* __restrict__ pl,
    float* __restrict__ out, int S) {
  int t    = threadIdx.x;
  int rowg = blockIdx.x * 32 + (t >> 3);
  int tile = rowg >> 7;
  int row  = rowg & 127;
  int dc   = (t & 7) << 3;

  float mv[8], lv[8];
  float M = -1e30f;
  for (int s = 0; s < S; ++s) {
    mv[s] = pm[(size_t)(tile * S + s) * 128 + row];
    lv[s] = pl[(size_t)(tile * S + s) * 128 + row];
    M = fmaxf(M, mv[s]);
  }
  float L = 0.f, w[8];
  for (int s = 0; s < S; ++s) {
    w[s] = exp2f(mv[s] - M);
    L += lv[s] * w[s];
  }
  float acc[8] = {0.f, 0.f, 0.f, 0.f, 0.f, 0.f, 0.f, 0.f};
  for (int s = 0; s < S; ++s) {
    const u16* p = po + (size_t)(tile * S + s) * 8192 + row * 64 + dc;
    uint4 raw = *(const uint4*)p;
    half8 x = __builtin_bit_cast(half8, raw);
#pragma unroll
    for (int k = 0; k < 8; ++k) acc[k] += w[s] * (float)x[k];
  }
  float invL = 1.0f / L;
  float* op = out + (size_t)rowg * 64 + dc;
  f32x4 o0 = (f32x4){acc[0], acc[1], acc[2], acc[3]};
  f32x4 o1 = (f32x4){acc[4], acc[5], acc[6], acc[7]};
  *(f32x4*)op       = o0 * invL;
  *(f32x4*)(op + 4) = o1 * invL;
}

// -------------------------------------------------------------- launch ----
extern "C" void kernel_launch(void* const* d_in, const int* in_sizes, int n_in,
                              void* d_out, int out_size, void* d_ws, size_t ws_size,
                              hipStream_t stream) {
  const float* Q = (const float*)d_in[0];
  const float* V = (const float*)d_in[1];
  float* out = (float*)d_out;

  const size_t convBytes = (size_t)2 * NB * SKV * DH * 2;  // vh+vt = 4 MB
  auto partBytes = [](int S) {
    return (size_t)NB * 32 * S * ((size_t)128 * 64 * 2 + 128 * 8);
  };
  int S = 8;
  while (S > 1 && ws_size < convBytes + partBytes(S)) S >>= 1;
  int kvLen = SKV / S;

  u16* vh = (u16*)d_ws;
  u16* vt = vh + (size_t)NB * SKV * DH;
  u16* po = vt + (size_t)NB * SKV * DH;
  float* pm = (float*)(po + (size_t)NB * 32 * S * 128 * 64);
  float* pl = pm + (size_t)NB * 32 * S * 128;

  prep_kernel<<<NB * 256, 256, 0, stream>>>(V, vh, vt);
  attn_kernel<<<NB * 32 * S, 256, 0, stream>>>(Q, vh, vt, po, pm, pl, S, kvLen);
  combine_kernel<<<NB * SQ / 32, 256, 0, stream>>>(po, pm, pl, out, S);
}